// Round 9
// baseline (72579.840 us; speedup 1.0000x reference)
//
#include <hip/hip_runtime.h>
#include <cstddef>

#define T_ 1024
#define B_ 64
#define D_ 256
#define L_ 1024
#define DC_ 256
#define H_ 256
#define A_ 256
#define G3 768
#define LQ 128   // L_/8 per block
#define NBLK 8   // blocks per batch

typedef unsigned int uint2v __attribute__((ext_vector_type(2)));
typedef float float4v __attribute__((ext_vector_type(4)));

__device__ __forceinline__ float bflo(unsigned int w) { return __uint_as_float(w << 16); }
__device__ __forceinline__ float bfhi(unsigned int w) { return __uint_as_float(w & 0xffff0000u); }
__device__ __forceinline__ unsigned short f2bf(float f) {
  unsigned int x = __float_as_uint(f);
  return (unsigned short)((x + 0x7fffu + ((x >> 16) & 1u)) >> 16);
}
__device__ __forceinline__ unsigned int packbf(float lo, float hi) {
  return (unsigned int)f2bf(lo) | ((unsigned int)f2bf(hi) << 16);
}
__device__ __forceinline__ float fast_tanh(float xx) {
  float e = __expf(2.0f * xx);
  return 1.0f - 2.0f / (e + 1.0f);
}
__device__ __forceinline__ float sigmoidf_(float xx) {
  return 1.0f / (1.0f + __expf(-xx));
}
__device__ __forceinline__ void st_agent_f(float* p, float v) {
  __hip_atomic_store(p, v, __ATOMIC_RELAXED, __HIP_MEMORY_SCOPE_AGENT);
}
__device__ __forceinline__ float ld_agent_f(const float* p) {
  return __hip_atomic_load(p, __ATOMIC_RELAXED, __HIP_MEMORY_SCOPE_AGENT);
}
__device__ __forceinline__ void st_agent_u64(unsigned long long* p, unsigned long long v) {
  __hip_atomic_store(p, v, __ATOMIC_RELAXED, __HIP_MEMORY_SCOPE_AGENT);
}
__device__ __forceinline__ unsigned long long ld_agent_u64(const unsigned long long* p) {
  return __hip_atomic_load(p, __ATOMIC_RELAXED, __HIP_MEMORY_SCOPE_AGENT);
}
__device__ __forceinline__ void add_agent_f(float* p, float v) {
  __hip_atomic_fetch_add(p, v, __ATOMIC_RELAXED, __HIP_MEMORY_SCOPE_AGENT);
}
// arrive: __syncthreads drains vmcnt (all agent stores/adds acked at the
// coherence point) before thread 0 bumps the counter.
__device__ __forceinline__ void group_arrive(unsigned int* ctrb) {
  __syncthreads();
  if (threadIdx.x == 0) {
    __hip_atomic_fetch_add(ctrb, 1u, __ATOMIC_RELAXED, __HIP_MEMORY_SCOPE_AGENT);
  }
}
__device__ __forceinline__ void group_wait(unsigned int* ctrb, unsigned int target) {
  if (threadIdx.x == 0) {
    while (__hip_atomic_load(ctrb, __ATOMIC_RELAXED, __HIP_MEMORY_SCOPE_AGENT) < target) {
      __builtin_amdgcn_s_sleep(2);
    }
  }
  __syncthreads();
}

__global__ void f2bf_kernel(const float* __restrict__ src,
                            unsigned short* __restrict__ dst, int n) {
  int i = (blockIdx.x * blockDim.x + threadIdx.x) * 4;
  if (i < n) {
    float4 v = *(const float4*)(src + i);
    ushort4 o;
    o.x = f2bf(v.x); o.y = f2bf(v.y); o.z = f2bf(v.z); o.w = f2bf(v.w);
    *(ushort4*)(dst + i) = o;
  }
}

// wihp[kb][r][c] : r in [0,512) rows of W_ih, c = g*32+jj -> col g*256+kb*32+jj
__global__ void pack_wihp_kernel(const float* __restrict__ W_ih,
                                 unsigned short* __restrict__ dst) {
  int idx = blockIdx.x * 256 + threadIdx.x;  // 8*512*96 = 393216
  int kb = idx / (512 * 96);
  int rem = idx % (512 * 96);
  int r = rem / 96, cj = rem % 96;
  int g = cj >> 5, jj = cj & 31;
  int j = g * 256 + kb * 32 + jj;
  dst[idx] = f2bf(W_ih[(size_t)r * G3 + j]);
}
__global__ void pack_whhp_kernel(const float* __restrict__ W_hh,
                                 unsigned short* __restrict__ dst) {
  int idx = blockIdx.x * 256 + threadIdx.x;  // 8*256*96 = 196608
  int kb = idx / (256 * 96);
  int rem = idx % (256 * 96);
  int r = rem / 96, cj = rem % 96;
  int g = cj >> 5, jj = cj & 31;
  int j = g * 256 + kb * 32 + jj;
  dst[idx] = f2bf(W_hh[(size_t)r * G3 + j]);
}

// ctxT[b][a][l] = bf16( sum_d context[b][l][d] * Wc[d][a] )
__global__ void ctx_proj_kernel(const float* __restrict__ context,
                                const float* __restrict__ Wc,
                                unsigned short* __restrict__ ctxT) {
  __shared__ float cs[4352];
  const int bid = blockIdx.x;
  const int b = bid >> 6;
  const int l0 = (bid & 63) << 4;
  const int tid = threadIdx.x;
  for (int idx = tid; idx < 16 * DC_; idx += 256) {
    int r = idx >> 8;
    int d = idx & 255;
    cs[r * DC_ + d] = context[((size_t)b * L_ + (l0 + r)) * DC_ + d];
  }
  __syncthreads();
  const int a = tid;
  float acc[16];
#pragma unroll
  for (int r = 0; r < 16; ++r) acc[r] = 0.0f;
  for (int d = 0; d < DC_; ++d) {
    float w = Wc[d * A_ + a];
#pragma unroll
    for (int r = 0; r < 16; ++r) acc[r] += cs[r * DC_ + d] * w;
  }
  __syncthreads();
#pragma unroll
  for (int r = 0; r < 16; ++r) cs[a * 17 + r] = acc[r];
  __syncthreads();
  for (int idx = tid; idx < 16 * A_; idx += 256) {
    int aa = idx >> 4;
    int r = idx & 15;
    ctxT[((size_t)b * A_ + aa) * L_ + l0 + r] = f2bf(cs[aa * 17 + r]);
  }
}

__global__ __launch_bounds__(512, 4) void encoder_kernel(
    const float* __restrict__ x, const int* __restrict__ lengths,
    const float* __restrict__ context, const int* __restrict__ ctx_lengths,
    const unsigned short* __restrict__ wx_b, const unsigned short* __restrict__ wh_b,
    const float* __restrict__ v,
    const unsigned short* __restrict__ wihp, const unsigned short* __restrict__ whhp,
    const float* __restrict__ b_ih, const float* __restrict__ b_hh,
    const unsigned short* __restrict__ ctxT, float* __restrict__ out,
    float* __restrict__ cadd, float* __restrict__ hx, unsigned int* __restrict__ ctr) {
  __shared__ __align__(16) unsigned short ctx_lds[A_ * LQ];  // 65536 B
  __shared__ __align__(16) float scratch[2048];              // 8192 B
  __shared__ __align__(16) float xt_s[D_];                   // 1024 B
  __shared__ __align__(16) float h_s[H_];                    // 1024 B
  __shared__ __align__(16) float c_s[DC_];                   // 1024 B
  __shared__ float q_s[A_];                                  // 1024 B
  __shared__ float pv_s[LQ];                                 // 512 B
  __shared__ float gatI[96], gatH[96];                       // 768 B
  // total ~79 KB -> 2 blocks/CU

  const int gb = blockIdx.x;
  const int b = gb >> 3, kb = gb & 7;  // kb == gb%8 -> per-XCD single kb slice
  const int tid = threadIdx.x;
  const int len = lengths[b];
  const int clen = ctx_lengths[b];
  const int lbase = kb * LQ;
  const unsigned short* ctxTb = ctxT + (size_t)b * A_ * L_;
  const float* ctxb = context + (size_t)b * L_ * DC_;
  const unsigned short* wihpk = wihp + (size_t)kb * (512 * 96);
  const unsigned short* whhpk = whhp + (size_t)kb * (256 * 96);
  float* hx_b = hx + (size_t)b * 256;
  unsigned int* ctr_b = ctr + b * 32;

  const int p8 = tid >> 6, i64 = tid & 63;    // q-phase / c-phase
  const int p16s = tid >> 5, i32 = tid & 31;  // scores
  const int pq = tid / 48, jp = tid % 48;     // GRU (tid<384)

  if (tid < 256) { h_s[tid] = 0.0f; q_s[tid] = 0.0f; }
  // per-thread v slice for scores (a-strip p16s*16..)
  float vreg[16];
#pragma unroll
  for (int i = 0; i < 16; ++i) vreg[i] = v[p16s * 16 + i];
  // per-thread biases for GRU cols (tid<96)
  float breg_i = 0.f, breg_h = 0.f;
  if (tid < 96) {
    int j = (tid >> 5) * 256 + kb * 32 + (tid & 31);
    breg_i = b_ih[j]; breg_h = b_hh[j];
  }
  // preload ctxT l-slice into LDS: [a][l_local(128)]
  for (int idx = tid; idx < 8192; idx += 512) {
    int a = idx >> 5;
    int lq = idx & 31;
    *(uint2v*)&ctx_lds[a * LQ + lq * 4] =
        *(const uint2v*)(ctxTb + (size_t)a * L_ + lbase + lq * 4);
  }
  // preload context slice into registers (bf16): thread = 16 l x 4 d
  uint2v creg[16];
#pragma unroll
  for (int i = 0; i < 16; ++i) {
    float4v cv = *(const float4v*)&ctxb[(size_t)(lbase + p8 * 16 + i) * DC_ + i64 * 4];
    creg[i].x = packbf(cv.x, cv.y);
    creg[i].y = packbf(cv.z, cv.w);
  }
  __syncthreads();

  for (int t = 0; t < len; ++t) {
    const int par = t & 1;
    float* caddb = cadd + ((size_t)(par * 64 + b)) * 288;
    float* cshadow = cadd + ((size_t)((1 - par) * 64 + b)) * 288;

    // ---- xt
    if (tid < 64) {
      *(float4v*)&xt_s[tid * 4] =
          *(const float4v*)&x[((size_t)t * B_ + b) * D_ + tid * 4];
    }
    __syncthreads();

    // ---- q[a] = xt@Wx + h@Wh (redundant per block; weights L2-hot per XCD)
    {
      const int a0 = i64 * 4, k0 = p8 * 32;
      float4v acc = {0.f, 0.f, 0.f, 0.f};
#pragma unroll
      for (int k = k0; k < k0 + 32; ++k) {
        float xv = xt_s[k];
        uint2v w = *(const uint2v*)(wx_b + (size_t)k * A_ + a0);
        acc.x += xv * bflo(w.x); acc.y += xv * bfhi(w.x);
        acc.z += xv * bflo(w.y); acc.w += xv * bfhi(w.y);
      }
#pragma unroll
      for (int k = k0; k < k0 + 32; ++k) {
        float hv = h_s[k];
        uint2v w = *(const uint2v*)(wh_b + (size_t)k * A_ + a0);
        acc.x += hv * bflo(w.x); acc.y += hv * bfhi(w.x);
        acc.z += hv * bflo(w.y); acc.w += hv * bfhi(w.y);
      }
      *(float4v*)&scratch[tid * 4] = acc;  // float idx = p8*256 + a
    }
    __syncthreads();
    if (tid < 256) {
      float q = 0.f;
#pragma unroll
      for (int p = 0; p < 8; ++p) q += scratch[p * 256 + tid];
      q_s[tid] = q;
    }
    __syncthreads();

    // ---- scores: (p16s, i32): 4 l's, a-strip 16 from LDS
    {
      const int l0 = i32 * 4;
      float4v acc = {0.f, 0.f, 0.f, 0.f};
      if (lbase + l0 < clen) {
        const unsigned short* basep = ctx_lds + p16s * 16 * LQ + l0;
#pragma unroll 4
        for (int aa = 0; aa < 16; ++aa) {
          uint2v w = *(const uint2v*)(basep + aa * LQ);
          float q = q_s[p16s * 16 + aa];
          float vv = vreg[aa];
          acc.x += vv * fast_tanh(bflo(w.x) + q);
          acc.y += vv * fast_tanh(bfhi(w.x) + q);
          acc.z += vv * fast_tanh(bflo(w.y) + q);
          acc.w += vv * fast_tanh(bfhi(w.y) + q);
        }
      }
      *(float4v*)&scratch[tid * 4] = acc;  // float idx = p16s*128 + l
    }
    __syncthreads();
    // ---- finalize: reduce 16 a-strips, exp (no max shift: |score|<=||v||_1), sum
    if (tid < 128) {
      float s = 0.f;
#pragma unroll
      for (int p = 0; p < 16; ++p) s += scratch[p * 128 + tid];
      float e = (lbase + tid < clen) ? __expf(s) : 0.f;
      pv_s[tid] = e;
      float sm = e;
#pragma unroll
      for (int off = 32; off; off >>= 1) sm += __shfl_xor(sm, off);
      if ((tid & 63) == 0) add_agent_f(caddb + 256, sm);  // csum
    }
    __syncthreads();

    // ---- c-partials from registers
    {
      float4v acc = {0.f, 0.f, 0.f, 0.f};
#pragma unroll
      for (int i = 0; i < 16; ++i) {
        float pv = pv_s[p8 * 16 + i];
        uint2v w = creg[i];
        acc.x += pv * bflo(w.x); acc.y += pv * bfhi(w.x);
        acc.z += pv * bflo(w.y); acc.w += pv * bfhi(w.y);
      }
      *(float4v*)&scratch[tid * 4] = acc;  // p8*256 + d
    }
    __syncthreads();
    if (tid < 256) {
      float cp = 0.f;
#pragma unroll
      for (int p = 0; p < 8; ++p) cp += scratch[p * 256 + tid];
      add_agent_f(caddb + tid, cp);
    }
    group_arrive(ctr_b);  // sync#1 flag; latency hidden under phase A

    // ---- GRU phase A (c-independent): gi_x and gh partials, 96 cols
    if (tid < 384) {
      const int r0 = pq * 32;
      float a0 = 0.f, a1 = 0.f, h0 = 0.f, h1 = 0.f;
#pragma unroll 8
      for (int i = 0; i < 32; ++i) {
        float zk = xt_s[r0 + i];
        unsigned int wi = *(const unsigned int*)(wihpk + (size_t)(r0 + i) * 96 + 2 * jp);
        a0 += zk * bflo(wi); a1 += zk * bfhi(wi);
        float hv = h_s[r0 + i];
        unsigned int wh = *(const unsigned int*)(whhpk + (size_t)(r0 + i) * 96 + 2 * jp);
        h0 += hv * bflo(wh); h1 += hv * bfhi(wh);
      }
      scratch[pq * 96 + 2 * jp] = a0; scratch[pq * 96 + 2 * jp + 1] = a1;
      scratch[768 + pq * 96 + 2 * jp] = h0; scratch[768 + pq * 96 + 2 * jp + 1] = h1;
    }
    __syncthreads();
    if (tid < 96) {
      float gi = breg_i, gh = breg_h;
#pragma unroll
      for (int p = 0; p < 8; ++p) {
        gi += scratch[p * 96 + tid];
        gh += scratch[768 + p * 96 + tid];
      }
      gatI[tid] = gi; gatH[tid] = gh;
    }
    group_wait(ctr_b, 16u * t + 8u);  // sync#1 wait

    // ---- read summed c + csum; normalize
    {
      unsigned long long cc = 0;
      if (tid < 128) cc = ld_agent_u64((const unsigned long long*)caddb + tid);
      if (tid == 128) pv_s[0] = ld_agent_f(caddb + 256);  // reuse pv_s[0] as csum slot
      __syncthreads();
      if (tid < 128) {
        float inv = 1.0f / pv_s[0];
        c_s[2 * tid] = __uint_as_float((unsigned int)cc) * inv;
        c_s[2 * tid + 1] = __uint_as_float((unsigned int)(cc >> 32)) * inv;
      }
      // zero the shadow parity buffer (idle this step) for step t+1
      if (tid < 16) st_agent_u64((unsigned long long*)(cshadow + kb * 32) + tid, 0ull);
      if (tid == 16 && kb == 0) st_agent_f(cshadow + 256, 0.0f);
    }
    __syncthreads();

    // ---- GRU phase B: gi_c partials (rows 256..511 of wihp with c)
    if (tid < 384) {
      const int r0 = pq * 32;
      float b0 = 0.f, b1 = 0.f;
#pragma unroll 8
      for (int i = 0; i < 32; ++i) {
        float zk = c_s[r0 + i];
        unsigned int wi =
            *(const unsigned int*)(wihpk + (size_t)(256 + r0 + i) * 96 + 2 * jp);
        b0 += zk * bflo(wi); b1 += zk * bfhi(wi);
      }
      scratch[pq * 96 + 2 * jp] = b0; scratch[pq * 96 + 2 * jp + 1] = b1;
    }
    __syncthreads();
    if (tid < 96) {
      float gi = gatI[tid];
#pragma unroll
      for (int p = 0; p < 8; ++p) gi += scratch[p * 96 + tid];
      gatI[tid] = gi;
    }
    __syncthreads();
    if (tid < 32) {
      float r = sigmoidf_(gatI[tid] + gatH[tid]);
      float u = sigmoidf_(gatI[32 + tid] + gatH[32 + tid]);
      float n = fast_tanh(gatI[64 + tid] + r * gatH[64 + tid]);
      float hn = u * h_s[kb * 32 + tid] + (1.0f - u) * n;
      st_agent_f(&hx_b[kb * 32 + tid], hn);
      __builtin_nontemporal_store(hn, &out[((size_t)t * B_ + b) * H_ + kb * 32 + tid]);
    }
    group_arrive(ctr_b);              // sync#2 flag
    group_wait(ctr_b, 16u * t + 16u); // sync#2 wait
    if (tid < 128) {
      unsigned long long hh = ld_agent_u64((const unsigned long long*)hx_b + tid);
      h_s[2 * tid] = __uint_as_float((unsigned int)hh);
      h_s[2 * tid + 1] = __uint_as_float((unsigned int)(hh >> 32));
    }
    __syncthreads();
  }

  // zero-fill masked timesteps: own 32-col slice
  {
    const int n = (T_ - len) * 32;
    for (int idx = tid; idx < n; idx += 512) {
      int tt = len + (idx >> 5);
      int ii = idx & 31;
      __builtin_nontemporal_store(0.0f, &out[((size_t)tt * B_ + b) * H_ + kb * 32 + ii]);
    }
  }
  // h_final: own slice
  if (tid < 32) {
    out[(size_t)T_ * B_ * H_ + (size_t)b * H_ + kb * 32 + tid] = h_s[kb * 32 + tid];
  }
}

extern "C" void kernel_launch(void* const* d_in, const int* in_sizes, int n_in,
                              void* d_out, int out_size, void* d_ws, size_t ws_size,
                              hipStream_t stream) {
  const float* x = (const float*)d_in[0];
  const int* lengths = (const int*)d_in[1];
  const float* context = (const float*)d_in[2];
  const int* ctx_lengths = (const int*)d_in[3];
  const float* Wc = (const float*)d_in[4];
  const float* Wx = (const float*)d_in[5];
  const float* Wh = (const float*)d_in[6];
  const float* v = (const float*)d_in[7];
  const float* W_ih = (const float*)d_in[8];
  const float* W_hh = (const float*)d_in[9];
  const float* b_ih = (const float*)d_in[10];
  const float* b_hh = (const float*)d_in[11];
  float* out = (float*)d_out;

  char* w = (char*)d_ws;
  unsigned short* ctxT = (unsigned short*)w;                        // 33,554,432 B
  unsigned short* wx_b = (unsigned short*)(w + 33554432);           // 131,072 B
  unsigned short* wh_b = (unsigned short*)(w + 33685504);           // 131,072 B
  unsigned short* wihp = (unsigned short*)(w + 33816576);           // 786,432 B
  unsigned short* whhp = (unsigned short*)(w + 34603008);           // 393,216 B
  float* hx = (float*)(w + 34996224);                               // 65,536 B
  unsigned int* ctr = (unsigned int*)(w + 35061760);                // 8,192 B
  float* cadd = (float*)(w + 35069952);                             // 147,456 B

  hipMemsetAsync(w + 35061760, 0, 8192 + 147456, stream);
  hipLaunchKernelGGL(f2bf_kernel, dim3(64), dim3(256), 0, stream, Wx, wx_b, D_ * A_);
  hipLaunchKernelGGL(f2bf_kernel, dim3(64), dim3(256), 0, stream, Wh, wh_b, H_ * A_);
  hipLaunchKernelGGL(pack_wihp_kernel, dim3(1536), dim3(256), 0, stream, W_ih, wihp);
  hipLaunchKernelGGL(pack_whhp_kernel, dim3(768), dim3(256), 0, stream, W_hh, whhp);
  hipLaunchKernelGGL(ctx_proj_kernel, dim3(B_ * (L_ / 16)), dim3(256), 0, stream,
                     context, Wc, ctxT);
  hipLaunchKernelGGL(encoder_kernel, dim3(B_ * NBLK), dim3(512), 0, stream,
                     x, lengths, context, ctx_lengths, wx_b, wh_b, v,
                     wihp, whhp, b_ih, b_hh, ctxT, out, cadd, hx, ctr);
}

// Round 10
// 54638.721 us; speedup vs baseline: 1.3284x; 1.3284x over previous
//
#include <hip/hip_runtime.h>
#include <cstddef>

#define T_ 1024
#define B_ 64
#define D_ 256
#define L_ 1024
#define DC_ 256
#define H_ 256
#define A_ 256
#define G3 768
#define LQ 256   // L_/4 per block
#define NBLK 4   // blocks per batch

typedef unsigned int uint2v __attribute__((ext_vector_type(2)));
typedef float float4v __attribute__((ext_vector_type(4)));
typedef float float2v __attribute__((ext_vector_type(2)));
typedef unsigned short ushort4v __attribute__((ext_vector_type(4)));

__device__ __forceinline__ float bflo(unsigned int w) { return __uint_as_float(w << 16); }
__device__ __forceinline__ float bfhi(unsigned int w) { return __uint_as_float(w & 0xffff0000u); }
__device__ __forceinline__ unsigned short f2bf(float f) {
  unsigned int x = __float_as_uint(f);
  return (unsigned short)((x + 0x7fffu + ((x >> 16) & 1u)) >> 16);
}
__device__ __forceinline__ float fast_tanh(float xx) {
  float e = __expf(2.0f * xx);
  return 1.0f - 2.0f / (e + 1.0f);
}
__device__ __forceinline__ float sigmoidf_(float xx) {
  return 1.0f / (1.0f + __expf(-xx));
}
__device__ __forceinline__ void st_agent_f(float* p, float v) {
  __hip_atomic_store(p, v, __ATOMIC_RELAXED, __HIP_MEMORY_SCOPE_AGENT);
}
__device__ __forceinline__ float ld_agent_f(const float* p) {
  return __hip_atomic_load(p, __ATOMIC_RELAXED, __HIP_MEMORY_SCOPE_AGENT);
}
__device__ __forceinline__ void group_arrive(unsigned int* ctrb) {
  __syncthreads();
  if (threadIdx.x == 0) {
    __hip_atomic_fetch_add(ctrb, 1u, __ATOMIC_RELAXED, __HIP_MEMORY_SCOPE_AGENT);
  }
}
__device__ __forceinline__ void group_wait(unsigned int* ctrb, unsigned int target) {
  if (threadIdx.x == 0) {
    while (__hip_atomic_load(ctrb, __ATOMIC_RELAXED, __HIP_MEMORY_SCOPE_AGENT) < target) {
      __builtin_amdgcn_s_sleep(2);
    }
  }
  __syncthreads();
}

__global__ void f2bf_kernel(const float* __restrict__ src,
                            unsigned short* __restrict__ dst, int n) {
  int i = (blockIdx.x * blockDim.x + threadIdx.x) * 4;
  if (i < n) {
    float4 v = *(const float4*)(src + i);
    ushort4 o;
    o.x = f2bf(v.x); o.y = f2bf(v.y); o.z = f2bf(v.z); o.w = f2bf(v.w);
    *(ushort4*)(dst + i) = o;
  }
}

// Pack W_ih columns per block-slice: dst[kb][r][jg] = W_ih[r][g*256 + kb*64 + jj]
__global__ void pack_wih_kernel(const float* __restrict__ W_ih,
                                unsigned short* __restrict__ dst) {
  int idx = blockIdx.x * 256 + threadIdx.x;  // 4*512*192 = 393216
  int kb = idx / (512 * 192);
  int rem = idx % (512 * 192);
  int r = rem / 192, jg = rem % 192;
  int g = jg >> 6, jj = jg & 63;
  int j = g * 256 + kb * 64 + jj;
  dst[idx] = f2bf(W_ih[(size_t)r * G3 + j]);
}
__global__ void pack_whh_kernel(const float* __restrict__ W_hh,
                                unsigned short* __restrict__ dst) {
  int idx = blockIdx.x * 256 + threadIdx.x;  // 4*256*192 = 196608
  int kb = idx / (256 * 192);
  int rem = idx % (256 * 192);
  int r = rem / 192, jg = rem % 192;
  int g = jg >> 6, jj = jg & 63;
  int j = g * 256 + kb * 64 + jj;
  dst[idx] = f2bf(W_hh[(size_t)r * G3 + j]);
}

__global__ __launch_bounds__(1024) void encoder_kernel(
    const float* __restrict__ x, const int* __restrict__ lengths,
    const float* __restrict__ context, const int* __restrict__ ctx_lengths,
    const float* __restrict__ Wc,
    const unsigned short* __restrict__ wx_b, const unsigned short* __restrict__ wh_b,
    const float* __restrict__ v,
    const unsigned short* __restrict__ wih_pk, const unsigned short* __restrict__ whh_pk,
    const float* __restrict__ b_ih, const float* __restrict__ b_hh,
    const unsigned short* __restrict__ ctx_bf, float* __restrict__ out,
    float* __restrict__ cpart, float* __restrict__ hx, unsigned int* __restrict__ ctr) {
  __shared__ __align__(16) unsigned short ctx_lds[A_ * LQ];  // 131072 B: [a][l_local]
  __shared__ __align__(16) float scratch[4096];              // 16384 B multipurpose
  __shared__ __align__(16) float xt_s[D_];
  __shared__ __align__(16) float h_s[H_];
  __shared__ __align__(16) float c_s[DC_];
  __shared__ float2 qv_s[A_];
  __shared__ float pv_s[LQ];
  __shared__ float gatI[192], gatH[192];
  __shared__ float bsl_i[192], bsl_h[192];
  __shared__ float wsum_l[4];

  const int gb = blockIdx.x;
  const int b = gb >> 2, kb = gb & 3;  // R5 mapping (weights measured L2-hot)
  const int tid = threadIdx.x;
  const int len = lengths[b];
  const int clen = ctx_lengths[b];
  const int lbase = kb * LQ;
  const float* ctxb = context + (size_t)b * L_ * DC_;
  const unsigned short* ctxbf_b = ctx_bf + (size_t)b * L_ * DC_;
  const unsigned short* wihp = wih_pk + (size_t)kb * (512 * 192);
  const unsigned short* whhp = whh_pk + (size_t)kb * (256 * 192);
  float* cpart_grp = cpart + (size_t)b * NBLK * 264;
  float* cpart_my = cpart_grp + kb * 264;
  float* hx_b = hx + (size_t)b * 256;
  unsigned int* ctr_b = ctr + b * 32;

  const int p16 = tid >> 6, i64 = tid & 63;
  const int pq = tid / 96, jc = tid % 96;  // GRU: 8 k-groups x 96 col-pairs

  if (tid < 256) { h_s[tid] = 0.0f; qv_s[tid] = make_float2(0.0f, v[tid]); }
  if (tid < 192) {
    int g = tid >> 6, jj = tid & 63;
    int j = g * 256 + kb * 64 + jj;
    bsl_i[tid] = b_ih[j]; bsl_h[tid] = b_hh[j];
  }
  __syncthreads();

  // ---- prologue: in-block projection -> ctx_lds[a][l_local] (bf16) ----
  // 16 tiles of 16 l-rows; stage context fp32 transposed [d][16] in scratch.
  {
    const int a = tid & 255, lq4 = tid >> 8;  // lq4 in 0..3 -> rows lq4*4..+3
    for (int tl = 0; tl < 16; ++tl) {
      for (int idx = tid; idx < 4096; idx += 1024) {
        int r = idx >> 8, d = idx & 255;
        scratch[d * 16 + r] = ctxb[(size_t)(lbase + tl * 16 + r) * DC_ + d];
      }
      __syncthreads();
      float a0 = 0.f, a1 = 0.f, a2 = 0.f, a3 = 0.f;
#pragma unroll 4
      for (int d = 0; d < 256; ++d) {
        float w = Wc[(size_t)d * A_ + a];
        const float* ps = &scratch[d * 16 + lq4 * 4];
        a0 += ps[0] * w; a1 += ps[1] * w; a2 += ps[2] * w; a3 += ps[3] * w;
      }
      int l0 = tl * 16 + lq4 * 4;
      ushort4v o; o.x = f2bf(a0); o.y = f2bf(a1); o.z = f2bf(a2); o.w = f2bf(a3);
      *(ushort4v*)&ctx_lds[a * LQ + l0] = o;
      __syncthreads();
    }
  }

  for (int t = 0; t < len; ++t) {
    // ---- xt
    if (tid < 64) {
      *(float4v*)&xt_s[tid * 4] =
          *(const float4v*)&x[((size_t)t * B_ + b) * D_ + tid * 4];
    }
    __syncthreads();

    // ---- q[a] = xt@Wx + h@Wh (full, redundant; weights L2-hot)
    {
      const int a0 = i64 * 4, k0 = p16 * 16;
      float4v acc = {0.f, 0.f, 0.f, 0.f};
#pragma unroll
      for (int k = k0; k < k0 + 16; ++k) {
        float xv = xt_s[k];
        uint2v w = *(const uint2v*)(wx_b + (size_t)k * A_ + a0);
        acc.x += xv * bflo(w.x); acc.y += xv * bfhi(w.x);
        acc.z += xv * bflo(w.y); acc.w += xv * bfhi(w.y);
      }
#pragma unroll
      for (int k = k0; k < k0 + 16; ++k) {
        float hv = h_s[k];
        uint2v w = *(const uint2v*)(wh_b + (size_t)k * A_ + a0);
        acc.x += hv * bflo(w.x); acc.y += hv * bfhi(w.x);
        acc.z += hv * bflo(w.y); acc.w += hv * bfhi(w.y);
      }
      *(float4v*)&scratch[tid * 4] = acc;
    }
    __syncthreads();
    if (tid < 256) {
      float q = 0.f;
#pragma unroll
      for (int p = 0; p < 16; ++p) q += scratch[p * 256 + tid];
      qv_s[tid].x = q;
    }
    __syncthreads();

    // ---- EARLY-ISSUE the c-pass context loads (bf16); they complete during
    // the scores phase below (drained by its trailing barrier).
    uint2v cstage[16];
#pragma unroll
    for (int i = 0; i < 16; ++i) {
      cstage[i] = *(const uint2v*)(ctxbf_b + (size_t)(lbase + p16 * 16 + i) * DC_ + i64 * 4);
    }

    // ---- scores from LDS: (p16,i64): 4 l's, a-strip 16
    {
      const int ll0 = i64 * 4;
      float4v acc = {0.f, 0.f, 0.f, 0.f};
      if (lbase + ll0 < clen) {
        const unsigned short* basep = ctx_lds + p16 * 16 * LQ + ll0;
#pragma unroll 4
        for (int aa = 0; aa < 16; ++aa) {
          uint2v w = *(const uint2v*)(basep + aa * LQ);
          float2 qv = qv_s[p16 * 16 + aa];
          acc.x += qv.y * fast_tanh(bflo(w.x) + qv.x);
          acc.y += qv.y * fast_tanh(bfhi(w.x) + qv.x);
          acc.z += qv.y * fast_tanh(bflo(w.y) + qv.x);
          acc.w += qv.y * fast_tanh(bfhi(w.y) + qv.x);
        }
      }
      *(float4v*)&scratch[tid * 4] = acc;
    }
    __syncthreads();
    // ---- finalize scores -> exp (no max shift: |score| <= ||v||_1 ~ 13), wave sums
    if (tid < 256) {
      float s = 0.f;
#pragma unroll
      for (int p = 0; p < 16; ++p) s += scratch[p * 256 + tid];
      int lg = lbase + tid;
      float e = (lg < clen) ? __expf(s) : 0.f;
      pv_s[tid] = e;
      float sm = e;
#pragma unroll
      for (int off = 32; off; off >>= 1) sm += __shfl_xor(sm, off);
      if ((tid & 63) == 0) wsum_l[tid >> 6] = sm;
    }
    __syncthreads();

    // ---- c-partials from staged bf16 context: pv[l]=0 beyond clen masks
    {
      float4v acc = {0.f, 0.f, 0.f, 0.f};
#pragma unroll
      for (int i = 0; i < 16; ++i) {
        float pv = pv_s[p16 * 16 + i];
        uint2v w = cstage[i];
        acc.x += pv * bflo(w.x); acc.y += pv * bfhi(w.x);
        acc.z += pv * bflo(w.y); acc.w += pv * bfhi(w.y);
      }
      *(float4v*)&scratch[tid * 4] = acc;
    }
    __syncthreads();
    if (tid < 256) {
      float cp = 0.f;
#pragma unroll
      for (int p = 0; p < 16; ++p) cp += scratch[p * 256 + tid];
      st_agent_f(&cpart_my[tid], cp);
    }
    if (tid == 0) {
      st_agent_f(&cpart_my[256], wsum_l[0] + wsum_l[1] + wsum_l[2] + wsum_l[3]);
    }
    group_arrive(ctr_b);  // sync#1 flag; latency hidden under phase A

    // ---- GRU phase A (c-independent): gi_x and gh partials for own 192 cols
    if (tid < 768) {
      const int r0 = pq * 32;
      float a0 = 0.f, a1 = 0.f, h0 = 0.f, h1 = 0.f;
#pragma unroll 8
      for (int i = 0; i < 32; ++i) {
        float zk = xt_s[r0 + i];
        unsigned int wi = *(const unsigned int*)(wihp + (size_t)(r0 + i) * 192 + 2 * jc);
        a0 += zk * bflo(wi); a1 += zk * bfhi(wi);
        float hv = h_s[r0 + i];
        unsigned int wh = *(const unsigned int*)(whhp + (size_t)(r0 + i) * 192 + 2 * jc);
        h0 += hv * bflo(wh); h1 += hv * bfhi(wh);
      }
      *(float2v*)&scratch[pq * 192 + 2 * jc] = float2v{a0, a1};
      *(float2v*)&scratch[1536 + pq * 192 + 2 * jc] = float2v{h0, h1};
    }
    __syncthreads();
    if (tid < 192) {
      float gi = bsl_i[tid], gh = bsl_h[tid];
#pragma unroll
      for (int p = 0; p < 8; ++p) {
        gi += scratch[p * 192 + tid];
        gh += scratch[1536 + p * 192 + tid];
      }
      gatI[tid] = gi; gatH[tid] = gh;
    }
    group_wait(ctr_b, 8u * t + 4u);  // sync#1 wait

    // ---- assemble c
    {
      float cc = 0.f;
      if (tid < 256) {
#pragma unroll
        for (int k2 = 0; k2 < 4; ++k2) cc += ld_agent_f(cpart_grp + k2 * 264 + tid);
      } else if (tid < 260) {
        wsum_l[tid - 256] = ld_agent_f(cpart_grp + (tid - 256) * 264 + 256);
      }
      __syncthreads();
      if (tid < 256) {
        c_s[tid] = cc / (wsum_l[0] + wsum_l[1] + wsum_l[2] + wsum_l[3]);
      }
    }
    __syncthreads();

    // ---- GRU phase B: gi_c partials (rows 256..511 of wihp with c)
    if (tid < 768) {
      const int r0 = pq * 32;
      float b0 = 0.f, b1 = 0.f;
#pragma unroll 8
      for (int i = 0; i < 32; ++i) {
        float zk = c_s[r0 + i];
        unsigned int wi =
            *(const unsigned int*)(wihp + (size_t)(256 + r0 + i) * 192 + 2 * jc);
        b0 += zk * bflo(wi); b1 += zk * bfhi(wi);
      }
      *(float2v*)&scratch[pq * 192 + 2 * jc] = float2v{b0, b1};
    }
    __syncthreads();
    if (tid < 192) {
      float gi = gatI[tid];
#pragma unroll
      for (int p = 0; p < 8; ++p) gi += scratch[p * 192 + tid];
      gatI[tid] = gi;
    }
    __syncthreads();
    if (tid < 64) {
      float r = sigmoidf_(gatI[tid] + gatH[tid]);
      float u = sigmoidf_(gatI[64 + tid] + gatH[64 + tid]);
      float n = fast_tanh(gatI[128 + tid] + r * gatH[128 + tid]);
      float hn = u * h_s[kb * 64 + tid] + (1.0f - u) * n;
      st_agent_f(&hx_b[kb * 64 + tid], hn);
      __builtin_nontemporal_store(hn, &out[((size_t)t * B_ + b) * H_ + kb * 64 + tid]);
    }
    group_arrive(ctr_b);             // sync#2 flag
    group_wait(ctr_b, 8u * t + 8u);  // sync#2 wait
    if (tid < 256) h_s[tid] = ld_agent_f(&hx_b[tid]);
    __syncthreads();
  }

  // zero-fill masked timesteps: own 64-col slice
  {
    const int n = (T_ - len) * 64;
    for (int idx = tid; idx < n; idx += 1024) {
      int tt = len + (idx >> 6);
      int ii = idx & 63;
      __builtin_nontemporal_store(0.0f, &out[((size_t)tt * B_ + b) * H_ + kb * 64 + ii]);
    }
  }
  // h_final: own slice
  if (tid < 64) {
    out[(size_t)T_ * B_ * H_ + (size_t)b * H_ + kb * 64 + tid] = h_s[kb * 64 + tid];
  }
}

extern "C" void kernel_launch(void* const* d_in, const int* in_sizes, int n_in,
                              void* d_out, int out_size, void* d_ws, size_t ws_size,
                              hipStream_t stream) {
  const float* x = (const float*)d_in[0];
  const int* lengths = (const int*)d_in[1];
  const float* context = (const float*)d_in[2];
  const int* ctx_lengths = (const int*)d_in[3];
  const float* Wc = (const float*)d_in[4];
  const float* Wx = (const float*)d_in[5];
  const float* Wh = (const float*)d_in[6];
  const float* v = (const float*)d_in[7];
  const float* W_ih = (const float*)d_in[8];
  const float* W_hh = (const float*)d_in[9];
  const float* b_ih = (const float*)d_in[10];
  const float* b_hh = (const float*)d_in[11];
  float* out = (float*)d_out;

  char* w = (char*)d_ws;
  unsigned short* ctx_bf = (unsigned short*)w;                      // 33,554,432 B
  unsigned short* wx_b = (unsigned short*)(w + 33554432);           // 131,072 B
  unsigned short* wh_b = (unsigned short*)(w + 33685504);           // 131,072 B
  unsigned short* wih_pk = (unsigned short*)(w + 33816576);         // 786,432 B
  unsigned short* whh_pk = (unsigned short*)(w + 34603008);         // 393,216 B
  float* cpart = (float*)(w + 34996224);                            // 270,336 B
  float* hx = (float*)(w + 35266560);                               // 65,536 B
  unsigned int* ctr = (unsigned int*)(w + 35332096);                // 8,192 B

  hipMemsetAsync(ctr, 0, 8192, stream);
  hipLaunchKernelGGL(f2bf_kernel, dim3(16384), dim3(256), 0, stream,
                     context, ctx_bf, B_ * L_ * DC_);
  hipLaunchKernelGGL(f2bf_kernel, dim3(64), dim3(256), 0, stream, Wx, wx_b, D_ * A_);
  hipLaunchKernelGGL(f2bf_kernel, dim3(64), dim3(256), 0, stream, Wh, wh_b, H_ * A_);
  hipLaunchKernelGGL(pack_wih_kernel, dim3(1536), dim3(256), 0, stream, W_ih, wih_pk);
  hipLaunchKernelGGL(pack_whh_kernel, dim3(768), dim3(256), 0, stream, W_hh, whh_pk);
  hipLaunchKernelGGL(encoder_kernel, dim3(B_ * NBLK), dim3(1024), 0, stream,
                     x, lengths, context, ctx_lengths, Wc, wx_b, wh_b, v,
                     wih_pk, whh_pk, b_ih, b_hh, ctx_bf, out, cpart, hx, ctr);
}